// Round 6
// baseline (312.411 us; speedup 1.0000x reference)
//
#include <hip/hip_runtime.h>
#include <hip/hip_bf16.h>
#include <stdint.h>
#include <math.h>

#define HIDDEN 768
#define BATCH 4
#define SEQ 8192
#define NQ 1024
#define PHS_KS 8

typedef __bf16 bf16;
typedef __bf16 bf16x4 __attribute__((ext_vector_type(4)));
typedef __bf16 bf16x8 __attribute__((ext_vector_type(8)));
typedef float f32x4 __attribute__((ext_vector_type(4)));

// General bijective XCD-chunked block-id swizzle (m204 formula, any grid size).
__device__ inline int xcd_swz() {
  const unsigned n = gridDim.x, o = blockIdx.x;
  const unsigned q = n >> 3, r = n & 7;
  const unsigned x = o & 7, k = o >> 3;
  return (int)((x < r ? x * (q + 1) : r * (q + 1) + (x - r) * q) + k);
}

#define GLOAD16(gptr, lptr)                                                   \
  __builtin_amdgcn_global_load_lds(                                           \
      (const __attribute__((address_space(1))) void*)(gptr),                  \
      (__attribute__((address_space(3))) void*)(lptr), 16, 0, 0)

// ---------------------------------------------------------------------------
// fp32 -> bf16 elementwise convert (float4 vectorized, grid-stride)
__global__ __launch_bounds__(256) void k_cvt(const float* __restrict__ in,
                                             bf16* __restrict__ out, int n4) {
  int stride = gridDim.x * blockDim.x;
  for (int i = blockIdx.x * blockDim.x + threadIdx.x; i < n4; i += stride) {
    float4 v = reinterpret_cast<const float4*>(in)[i];
    bf16x4 o = {(bf16)v.x, (bf16)v.y, (bf16)v.z, (bf16)v.w};
    reinterpret_cast<bf16x4*>(out)[i] = o;
  }
}

// ---------------------------------------------------------------------------
// [R][C] fp32 -> [C][R] bf16 tiled transpose-convert (weights).
__global__ __launch_bounds__(256) void k_transpose_w(
    const float* __restrict__ in, bf16* __restrict__ out, int R, int C) {
  __shared__ float tile[32][33];
  const int c0 = blockIdx.x * 32, r0 = blockIdx.y * 32;
  const int tx = threadIdx.x & 31, ty = threadIdx.x >> 5;  // 32 x 8
#pragma unroll
  for (int i = 0; i < 32; i += 8)
    tile[ty + i][tx] = in[(long)(r0 + ty + i) * C + (c0 + tx)];
  __syncthreads();
#pragma unroll
  for (int i = 0; i < 32; i += 8)
    out[(long)(c0 + ty + i) * R + (r0 + tx)] = (bf16)tile[tx][ty + i];
}

// ---------------------------------------------------------------------------
// Fused: hs fp32 [B*S][H] -> hsb bf16 (same layout) + hsT bf16 [B][H][S].
__global__ __launch_bounds__(256) void k_cvt_hs_dual(const float* __restrict__ hs,
                                                     bf16* __restrict__ hsb,
                                                     bf16* __restrict__ hsT) {
  __shared__ float T[32][65];
  const int h0 = blockIdx.x * 64;
  const int s0g = blockIdx.y * 32;  // global row in [0, B*S)
  const int b = s0g >> 13;          // / 8192
  const int sIn = s0g & 8191;
  const int t = threadIdx.x;
  const int r = t >> 3, c = (t & 7) * 8;

  const float* src = hs + (long)(s0g + r) * HIDDEN + h0 + c;
  float4 v0 = *reinterpret_cast<const float4*>(src);
  float4 v1 = *reinterpret_cast<const float4*>(src + 4);
  T[r][c + 0] = v0.x; T[r][c + 1] = v0.y; T[r][c + 2] = v0.z; T[r][c + 3] = v0.w;
  T[r][c + 4] = v1.x; T[r][c + 5] = v1.y; T[r][c + 6] = v1.z; T[r][c + 7] = v1.w;

  bf16x8 o = {(bf16)v0.x, (bf16)v0.y, (bf16)v0.z, (bf16)v0.w,
              (bf16)v1.x, (bf16)v1.y, (bf16)v1.z, (bf16)v1.w};
  *reinterpret_cast<bf16x8*>(hsb + (long)(s0g + r) * HIDDEN + h0 + c) = o;

  __syncthreads();
  const int hh = t >> 2, ss = (t & 3) * 8;
  bf16x8 o2;
#pragma unroll
  for (int k = 0; k < 8; ++k) o2[k] = (bf16)T[ss + k][hh];
  *reinterpret_cast<bf16x8*>(hsT + ((long)b * HIDDEN + h0 + hh) * SEQ + sIn + ss) = o2;
}

// bqk[h] = sum_d bq[d] * Wk[h][d]
__global__ __launch_bounds__(64) void k_gemv_bqk(const float* __restrict__ Wk,
                                                 const float* __restrict__ bq,
                                                 float* __restrict__ bqk) {
  const int h = blockIdx.x, l = threadIdx.x;
  float s = 0.0f;
#pragma unroll
  for (int d = l; d < HIDDEN; d += 64) s += bq[d] * Wk[(long)h * HIDDEN + d];
#pragma unroll
  for (int o = 32; o > 0; o >>= 1) s += __shfl_xor(s, o);
  if (l == 0) bqk[h] = s;
}

// ---------------------------------------------------------------------------
// Small-GEMM workhorse (verified round-5 structure, MODE 0 only used):
// C[M,N] = (A.B^T)*scale + bias[col]; 128x128 tile, BK=32, dbuf 2-phase,
// LDS-bounced bf16 stores / direct fp32 stores.
template <typename OUT>
__global__ __launch_bounds__(256) void k_gemm_bt(
    const bf16* __restrict__ A, const bf16* __restrict__ B, OUT* __restrict__ C,
    const float* __restrict__ bias, int N, int K, float scale,
    int nx, int ny, long strA, long strB, long strC) {
  const int id = xcd_swz();
  const int col = id % nx;
  const int row = (id / nx) % ny;
  const int z = id / (nx * ny);

  __shared__ bf16 smem[16384];

  const int tid = threadIdx.x;
  const int lane = tid & 63, wave = tid >> 6;
  const int wr = wave >> 1, wc = wave & 1;
  const int lr = lane & 15, lk = (lane >> 4) * 8, lg = (lane >> 4) * 4;

  const bf16* At = A + (long)z * strA + (long)row * 128 * K;
  const bf16* Bt = B + (long)z * strB + (long)col * 128 * K;

#define STAGE_TILE(buf, k0)                                                   \
  {                                                                           \
    bf16* dA = smem + (buf) * 4096;                                           \
    bf16* dB = smem + 8192 + (buf) * 4096;                                    \
    _Pragma("unroll") for (int h = 0; h < 2; ++h) {                           \
      const int cch = tid + h * 256;                                          \
      const int rr = cch >> 2, cc = (cch & 3) * 8;                            \
      GLOAD16(At + (long)rr * K + (k0) + cc, (char*)dA + cch * 16);           \
      GLOAD16(Bt + (long)rr * K + (k0) + cc, (char*)dB + cch * 16);           \
    }                                                                         \
  }

  STAGE_TILE(0, 0);
  __syncthreads();

  f32x4 acc[4][4] = {};
  const int nt = K / 32;
  int cur = 0;
  for (int t = 0; t < nt; ++t) {
    if (t + 1 < nt) STAGE_TILE(cur ^ 1, (t + 1) * 32);
    const bf16* rA = smem + cur * 4096;
    const bf16* rB = smem + 8192 + cur * 4096;
    bf16x8 af[4], bfr[4];
#pragma unroll
    for (int m = 0; m < 4; ++m)
      af[m] = *reinterpret_cast<const bf16x8*>(&rA[(wr * 64 + m * 16 + lr) * 32 + lk]);
#pragma unroll
    for (int n = 0; n < 4; ++n)
      bfr[n] = *reinterpret_cast<const bf16x8*>(&rB[(wc * 64 + n * 16 + lr) * 32 + lk]);
#pragma unroll
    for (int m = 0; m < 4; ++m)
#pragma unroll
      for (int n = 0; n < 4; ++n)
        acc[m][n] = __builtin_amdgcn_mfma_f32_16x16x32_bf16(af[m], bfr[n], acc[m][n], 0, 0, 0);
    __syncthreads();
    cur ^= 1;
  }
#undef STAGE_TILE

  if constexpr (__is_same(OUT, float)) {
    float* Cb = (float*)C + (long)z * strC;
#pragma unroll
    for (int m = 0; m < 4; ++m)
#pragma unroll
      for (int n = 0; n < 4; ++n) {
        const int gc = col * 128 + wc * 64 + n * 16 + lr;
        const float bv = bias ? bias[gc] : 0.0f;
#pragma unroll
        for (int j = 0; j < 4; ++j) {
          const int gr = row * 128 + wr * 64 + m * 16 + lg + j;
          Cb[(long)gr * N + gc] = acc[m][n][j] * scale + bv;
        }
      }
  } else {
#pragma unroll
    for (int m = 0; m < 4; ++m)
#pragma unroll
      for (int n = 0; n < 4; ++n) {
        const int gc = col * 128 + wc * 64 + n * 16 + lr;
        const float bv = bias ? bias[gc] : 0.0f;
#pragma unroll
        for (int j = 0; j < 4; ++j)
          smem[(wr * 64 + m * 16 + lg + j) * 128 + wc * 64 + n * 16 + lr] =
              (bf16)(acc[m][n][j] * scale + bv);
      }
    __syncthreads();
    OUT* Cb = C + (long)z * strC;
    const long rb = (long)row * 128, cb = (long)col * 128;
#pragma unroll
    for (int i = 0; i < 8; ++i) {
      const int ch = tid + i * 256;
      const int rr = ch >> 4;
      const int ce = (ch & 15) * 8;
      *reinterpret_cast<bf16x8*>(&Cb[(rb + rr) * N + cb + ce]) =
          *reinterpret_cast<const bf16x8*>(smem + ch * 8);
    }
  }
}

// ---------------------------------------------------------------------------
// Pipelined 256x128 GEMM (counted-vmcnt, raw barriers, swizzled LDS, setprio).
// MODE 1: scores  Pr = exp((tmp.hsb^T)*scale + maskbias) + rowsum partials.
// MODE 2: PHS     Cp[kc] = P-chunk . hsT^T (bf16 partial).
// Geometry: BM=256, BN=128, BK=64 (2 K-halves of 32), 8 waves (2Mx4N),
// LDS: A slabs 2buf x 2half x 16KB + B slabs 2x2x8KB = 96 KB.
// Swizzle: 16B-slot s' = s ^ (r&3) ^ ((r>>2)&3), inverse on global source,
// applied on ds_read (both-sides involution).
template <int MODE>
__global__ __launch_bounds__(512, 2) void k_gemm8(
    const bf16* __restrict__ A, const bf16* __restrict__ B, bf16* __restrict__ C,
    const float* __restrict__ mask, float* __restrict__ rspart, float scale) {
  __shared__ bf16 smem[49152];  // 96 KB
  const int tid = threadIdx.x;
  const int lane = tid & 63;
  const int wave = tid >> 6;   // 0..7
  const int wm = wave >> 2;    // 0..1 : M-half (128 rows)
  const int wn = wave & 3;     // 0..3 : 32-col slice
  const int lr = lane & 15;
  const int l16 = lane >> 4;   // 0..3

  const int id = xcd_swz();
  const bf16* Ap;
  const bf16* Bp;
  long ldA, ldB;
  int col, row, z, kc = 0, NT;
  if constexpr (MODE == 1) {
    row = id & 3; col = (id >> 2) & 63; z = id >> 8;      // 4 x 64 x 4 = 1024
    Ap = A + ((long)z * NQ + row * 256) * HIDDEN; ldA = HIDDEN;
    Bp = B + ((long)z * SEQ + col * 128) * HIDDEN; ldB = HIDDEN;
    NT = 12;                                              // K = 768
  } else {
    col = id % 6; int r1 = id / 6; row = r1 & 3; int r2 = r1 >> 2;
    z = r2 & 3; kc = r2 >> 2;                             // 6 x 4 x 4 x 8 = 768
    Ap = A + ((long)z * NQ + row * 256) * SEQ + kc * (SEQ / PHS_KS); ldA = SEQ;
    Bp = B + ((long)z * HIDDEN + col * 128) * SEQ + kc * (SEQ / PHS_KS); ldB = SEQ;
    NT = (SEQ / PHS_KS) / 64;                             // 16
  }

  // stage K-tile kt, K-half kh into buf kt&1: A 2 chunks + B 1 chunk per thread
  auto STG = [&](int kt, int kh) {
    const int d = kt & 1;
    const int k0 = kt * 64 + kh * 32;
    bf16* sA = smem + (d * 2 + kh) * 8192;
    bf16* sB = smem + 32768 + (d * 2 + kh) * 4096;
#pragma unroll
    for (int h = 0; h < 2; ++h) {
      const int c = tid + h * 512;
      const int r = c >> 2;
      const int slot = (c & 3) ^ (r & 3) ^ ((r >> 2) & 3);
      GLOAD16(Ap + (long)r * ldA + k0 + slot * 8, (char*)sA + c * 16);
    }
    {
      const int c = tid;
      const int r = c >> 2;
      const int slot = (c & 3) ^ (r & 3) ^ ((r >> 2) & 3);
      GLOAD16(Bp + (long)r * ldB + k0 + slot * 8, (char*)sB + c * 16);
    }
  };

  f32x4 acc[8][2] = {};

  STG(0, 0);
  STG(0, 1);

#pragma unroll 1
  for (int T = 0; T < NT; ++T) {
    const int d = T & 1;
    asm volatile("" ::: "memory");
    __builtin_amdgcn_s_barrier();  // B0: all reads of tile T-1 done -> its buf free
    if (T + 1 < NT) { STG(T + 1, 0); STG(T + 1, 1); }
    if (T + 1 < NT) asm volatile("s_waitcnt vmcnt(9)" ::: "memory");  // STG(T,0) landed
    else            asm volatile("s_waitcnt vmcnt(3)" ::: "memory");
    __builtin_amdgcn_s_barrier();  // B1: every thread's kh0 stage landed
    asm volatile("" ::: "memory");
#pragma unroll
    for (int kh = 0; kh < 2; ++kh) {
      if (kh == 1) {
        if (T + 1 < NT) asm volatile("s_waitcnt vmcnt(6)" ::: "memory");  // STG(T,1)
        else            asm volatile("s_waitcnt vmcnt(0)" ::: "memory");
        __builtin_amdgcn_s_barrier();  // B2
        asm volatile("" ::: "memory");
      }
      const bf16* sA = smem + (d * 2 + kh) * 8192;
      const bf16* sB = smem + 32768 + (d * 2 + kh) * 4096;
      bf16x8 bfr[2], af[8];
#pragma unroll
      for (int n = 0; n < 2; ++n) {
        const int rb = wn * 32 + n * 16 + lr;
        const int slot = l16 ^ (rb & 3) ^ ((rb >> 2) & 3);
        bfr[n] = *reinterpret_cast<const bf16x8*>(sB + rb * 32 + slot * 8);
      }
#pragma unroll
      for (int m = 0; m < 8; ++m) {
        const int ra = wm * 128 + m * 16 + lr;
        const int slot = l16 ^ (ra & 3) ^ ((ra >> 2) & 3);
        af[m] = *reinterpret_cast<const bf16x8*>(sA + ra * 32 + slot * 8);
      }
      __builtin_amdgcn_s_setprio(1);
#pragma unroll
      for (int m = 0; m < 8; ++m)
#pragma unroll
        for (int n = 0; n < 2; ++n)
          acc[m][n] = __builtin_amdgcn_mfma_f32_16x16x32_bf16(af[m], bfr[n], acc[m][n], 0, 0, 0);
      __builtin_amdgcn_s_setprio(0);
    }
  }

  // ---- epilogue: bounce C tile [256][128] bf16 through LDS ----
  asm volatile("" ::: "memory");
  __builtin_amdgcn_s_barrier();
  asm volatile("" ::: "memory");

  float rs[8][4];
  if constexpr (MODE == 1) {
#pragma unroll
    for (int m = 0; m < 8; ++m)
#pragma unroll
      for (int j = 0; j < 4; ++j) rs[m][j] = 0.0f;
  }
#pragma unroll
  for (int m = 0; m < 8; ++m)
#pragma unroll
    for (int n = 0; n < 2; ++n) {
      const int gc = wn * 32 + n * 16 + lr;
      float mbv = 0.0f;
      if constexpr (MODE == 1)
        mbv = (1.0f - mask[(long)z * SEQ + col * 128 + gc]) * -10000.0f;
#pragma unroll
      for (int j = 0; j < 4; ++j) {
        float v = acc[m][n][j];
        if constexpr (MODE == 1) {
          v = expf(v * scale + mbv);
          rs[m][j] += v;
        }
        smem[(wm * 128 + m * 16 + l16 * 4 + j) * 128 + gc] = (bf16)v;
      }
    }
  if constexpr (MODE == 1) {
#pragma unroll
    for (int m = 0; m < 8; ++m)
#pragma unroll
      for (int j = 0; j < 4; ++j) {
        float v = rs[m][j];
        v += __shfl_xor(v, 1); v += __shfl_xor(v, 2);
        v += __shfl_xor(v, 4); v += __shfl_xor(v, 8);
        if (lr == 0)
          rspart[((long)z * NQ + row * 256 + wm * 128 + m * 16 + l16 * 4 + j) * 256 +
                 col * 4 + wn] = v;
      }
  }
  __builtin_amdgcn_s_barrier();
  asm volatile("" ::: "memory");

  bf16* Cb;
  long ldc;
  if constexpr (MODE == 1) {
    Cb = C + ((long)z * NQ + row * 256) * SEQ + col * 128;
    ldc = SEQ;
  } else {
    Cb = C + ((long)(kc * BATCH + z) * NQ + row * 256) * HIDDEN + col * 128;
    ldc = HIDDEN;
  }
#pragma unroll
  for (int i = 0; i < 8; ++i) {
    const int ch = tid + i * 512;   // 4096 chunks of 16B = 256x128 bf16
    const int rr = ch >> 4;
    const int ce = (ch & 15) * 8;
    *reinterpret_cast<bf16x8*>(&Cb[(long)rr * ldc + ce]) =
        *reinterpret_cast<const bf16x8*>(smem + ch * 8);
  }
}

// rowsum[row] = sum of 256 partial slots (one wave per row)
__global__ __launch_bounds__(256) void k_rowsum(const float* __restrict__ rp,
                                                float* __restrict__ rs) {
  const int w = threadIdx.x >> 6, l = threadIdx.x & 63;
  const int row = blockIdx.x * 4 + w;
  const float* base = rp + (long)row * 256;
  float v = base[l] + base[l + 64] + base[l + 128] + base[l + 192];
#pragma unroll
  for (int o = 32; o > 0; o >>= 1) v += __shfl_xor(v, o);
  if (l == 0) rs[row] = v;
}

// ctx1 = (sum of 8 bf16 partials) / rowsum[row]
__global__ __launch_bounds__(256) void k_reduce8(const bf16* __restrict__ p,
                                                 const float* __restrict__ rs,
                                                 bf16* __restrict__ out, int n8) {
  const long NB = (long)BATCH * NQ * HIDDEN;
  const int stride = gridDim.x * blockDim.x;
  for (int i = blockIdx.x * blockDim.x + threadIdx.x; i < n8; i += stride) {
    float acc[8] = {};
#pragma unroll
    for (int k = 0; k < PHS_KS; ++k) {
      bf16x8 v = reinterpret_cast<const bf16x8*>(p + k * NB)[i];
#pragma unroll
      for (int j = 0; j < 8; ++j) acc[j] += (float)v[j];
    }
    const float inv = 1.0f / rs[i / 96];  // 96 vec8-chunks per 768-col row
    bf16x8 o;
#pragma unroll
    for (int j = 0; j < 8; ++j) o[j] = (bf16)(acc[j] * inv);
    reinterpret_cast<bf16x8*>(out)[i] = o;
  }
}

// ---------------------------------------------------------------------------
extern "C" void kernel_launch(void* const* d_in, const int* in_sizes, int n_in,
                              void* d_out, int out_size, void* d_ws, size_t ws_size,
                              hipStream_t stream) {
  const float* hs = (const float*)d_in[0];    // [B,S,H]
  const float* qu = (const float*)d_in[1];    // [B,Q,H]
  const float* mask = (const float*)d_in[2];  // [B,S]
  const float* Wq = (const float*)d_in[3];
  const float* bq = (const float*)d_in[4];
  const float* Wk = (const float*)d_in[5];
  const float* Wv = (const float*)d_in[7];
  const float* bv = (const float*)d_in[8];
  float* out = (float*)d_out;  // [B,Q,H] fp32
  // bk (d_in[6]) adds a softmax-row-constant -> cancels exactly.

  const size_t HS_N = (size_t)BATCH * SEQ * HIDDEN;
  const size_t QU_N = (size_t)BATCH * NQ * HIDDEN;
  const size_t W_N = (size_t)HIDDEN * HIDDEN;
  const size_t P_N = (size_t)BATCH * NQ * SEQ;

  char* ws = (char*)d_ws;
  size_t off = 0;
  auto alloc = [&](size_t bytes) {
    char* p = ws + off;
    off += (bytes + 255) & ~(size_t)255;
    return p;
  };

  // regionA: hsb (live through scores) / PHS partials (after) — exact overlap
  char* regionA = alloc(HS_N * 2);
  bf16* hsb = (bf16*)regionA;
  bf16* Ppart = (bf16*)regionA;         // PHS_KS * QU_N bf16 = HS_N*2 bytes
  bf16* hsT = (bf16*)alloc(HS_N * 2);   // [B][H][S]
  bf16* Pr = (bf16*)alloc(P_N * 2);     // unnormalized probs exp(s+mb)
  bf16* qub = (bf16*)alloc(QU_N * 2);
  bf16* tmpb = (bf16*)alloc(QU_N * 2);  // folded query: qu.(Wq.Wk^T) + bq.Wk^T
  bf16* ctx1 = (bf16*)alloc(QU_N * 2);  // (P.hs)/rowsum
  bf16* Wkb = (bf16*)alloc(W_N * 2);
  bf16* Wqb = (bf16*)alloc(W_N * 2);
  bf16* WvT = (bf16*)alloc(W_N * 2);
  bf16* Mt = (bf16*)alloc(W_N * 2);     // Wk.Wq^T
  float* bqk = (float*)alloc(HIDDEN * 4);
  float* rspart = (float*)alloc((size_t)BATCH * NQ * 256 * 4);  // 4 MB
  float* rowsum = (float*)alloc((size_t)BATCH * NQ * 4);

  // 1) converts + fused hs prep
  k_cvt<<<dim3(1024), dim3(256), 0, stream>>>(qu, qub, (int)(QU_N / 4));
  k_cvt<<<dim3(576), dim3(256), 0, stream>>>(Wk, Wkb, (int)(W_N / 4));
  k_cvt<<<dim3(576), dim3(256), 0, stream>>>(Wq, Wqb, (int)(W_N / 4));
  k_transpose_w<<<dim3(24, 24), dim3(256), 0, stream>>>(Wv, WvT, HIDDEN, HIDDEN);
  k_cvt_hs_dual<<<dim3(12, 1024), dim3(256), 0, stream>>>(hs, hsb, hsT);
  k_gemv_bqk<<<dim3(768), dim3(64), 0, stream>>>(Wk, bq, bqk);

  // 2) Mt = Wk.Wq^T  [768x768]
  k_gemm_bt<bf16><<<dim3(36), dim3(256), 0, stream>>>(
      Wkb, Wqb, Mt, nullptr, HIDDEN, HIDDEN, 1.0f, 6, 6, 0, 0, 0);

  // 3) folded query: tmp = qub.Mt^T + bqk  [4096x768]
  k_gemm_bt<bf16><<<dim3(192), dim3(256), 0, stream>>>(
      qub, Mt, tmpb, bqk, HIDDEN, HIDDEN, 1.0f, 6, 32, 0, 0, 0);

  // 4) scores: Pr = exp(tmp.hsb^T/sqrt(H) + maskbias), rowsum partials
  const float qkscale = 1.0f / sqrtf((float)HIDDEN);
  k_gemm8<1><<<dim3(1024), dim3(512), 0, stream>>>(tmpb, hsb, Pr, mask, rspart, qkscale);
  k_rowsum<<<dim3(BATCH * NQ / 4), dim3(256), 0, stream>>>(rspart, rowsum);

  // 5) PHS partials: Ppart[kc] = P[:, kc-chunk] . hsT^T  (overwrites dead hsb)
  k_gemm8<2><<<dim3(768), dim3(512), 0, stream>>>(Pr, hsT, Ppart, nullptr, nullptr, 1.0f);

  // 6) ctx1 = (sum partials) / rowsum
  k_reduce8<<<dim3(1536), dim3(256), 0, stream>>>(Ppart, rowsum, ctx1, (int)(QU_N / 8));

  // 7) V-fold: out = ctx1.Wv + bv  (sum_j p = 1 makes +bv exact)
  k_gemm_bt<float><<<dim3(192), dim3(256), 0, stream>>>(
      ctx1, WvT, out, bv, HIDDEN, HIDDEN, 1.0f, 6, 32, 0, 0, 0);
}

// Round 7
// 252.605 us; speedup vs baseline: 1.2368x; 1.2368x over previous
//
#include <hip/hip_runtime.h>
#include <hip/hip_bf16.h>
#include <stdint.h>
#include <math.h>

#define HIDDEN 768
#define BATCH 4
#define SEQ 8192
#define NQ 1024
#define PHS_KS 8

typedef __bf16 bf16;
typedef __bf16 bf16x4 __attribute__((ext_vector_type(4)));
typedef __bf16 bf16x8 __attribute__((ext_vector_type(8)));
typedef float f32x4 __attribute__((ext_vector_type(4)));

// General bijective XCD-chunked block-id swizzle (m204 formula, any grid size).
__device__ inline int xcd_swz() {
  const unsigned n = gridDim.x, o = blockIdx.x;
  const unsigned q = n >> 3, r = n & 7;
  const unsigned x = o & 7, k = o >> 3;
  return (int)((x < r ? x * (q + 1) : r * (q + 1) + (x - r) * q) + k);
}

#define GLOAD16(gptr, lptr)                                                   \
  __builtin_amdgcn_global_load_lds(                                           \
      (const __attribute__((address_space(1))) void*)(gptr),                  \
      (__attribute__((address_space(3))) void*)(lptr), 16, 0, 0)

#define FENCE asm volatile("" ::: "memory")

// ---------------------------------------------------------------------------
// fp32 -> bf16 elementwise convert (float4 vectorized, grid-stride)
__global__ __launch_bounds__(256) void k_cvt(const float* __restrict__ in,
                                             bf16* __restrict__ out, int n4) {
  int stride = gridDim.x * blockDim.x;
  for (int i = blockIdx.x * blockDim.x + threadIdx.x; i < n4; i += stride) {
    float4 v = reinterpret_cast<const float4*>(in)[i];
    bf16x4 o = {(bf16)v.x, (bf16)v.y, (bf16)v.z, (bf16)v.w};
    reinterpret_cast<bf16x4*>(out)[i] = o;
  }
}

// ---------------------------------------------------------------------------
// [R][C] fp32 -> [C][R] bf16 tiled transpose-convert (weights).
__global__ __launch_bounds__(256) void k_transpose_w(
    const float* __restrict__ in, bf16* __restrict__ out, int R, int C) {
  __shared__ float tile[32][33];
  const int c0 = blockIdx.x * 32, r0 = blockIdx.y * 32;
  const int tx = threadIdx.x & 31, ty = threadIdx.x >> 5;  // 32 x 8
#pragma unroll
  for (int i = 0; i < 32; i += 8)
    tile[ty + i][tx] = in[(long)(r0 + ty + i) * C + (c0 + tx)];
  __syncthreads();
#pragma unroll
  for (int i = 0; i < 32; i += 8)
    out[(long)(c0 + ty + i) * R + (r0 + tx)] = (bf16)tile[tx][ty + i];
}

// ---------------------------------------------------------------------------
// Fused: hs fp32 [B*S][H] -> hsb bf16 (same layout) + hsT bf16 [B][H][S].
__global__ __launch_bounds__(256) void k_cvt_hs_dual(const float* __restrict__ hs,
                                                     bf16* __restrict__ hsb,
                                                     bf16* __restrict__ hsT) {
  __shared__ float T[32][65];
  const int h0 = blockIdx.x * 64;
  const int s0g = blockIdx.y * 32;  // global row in [0, B*S)
  const int b = s0g >> 13;          // / 8192
  const int sIn = s0g & 8191;
  const int t = threadIdx.x;
  const int r = t >> 3, c = (t & 7) * 8;

  const float* src = hs + (long)(s0g + r) * HIDDEN + h0 + c;
  float4 v0 = *reinterpret_cast<const float4*>(src);
  float4 v1 = *reinterpret_cast<const float4*>(src + 4);
  T[r][c + 0] = v0.x; T[r][c + 1] = v0.y; T[r][c + 2] = v0.z; T[r][c + 3] = v0.w;
  T[r][c + 4] = v1.x; T[r][c + 5] = v1.y; T[r][c + 6] = v1.z; T[r][c + 7] = v1.w;

  bf16x8 o = {(bf16)v0.x, (bf16)v0.y, (bf16)v0.z, (bf16)v0.w,
              (bf16)v1.x, (bf16)v1.y, (bf16)v1.z, (bf16)v1.w};
  *reinterpret_cast<bf16x8*>(hsb + (long)(s0g + r) * HIDDEN + h0 + c) = o;

  __syncthreads();
  const int hh = t >> 2, ss = (t & 3) * 8;
  bf16x8 o2;
#pragma unroll
  for (int k = 0; k < 8; ++k) o2[k] = (bf16)T[ss + k][hh];
  *reinterpret_cast<bf16x8*>(hsT + ((long)b * HIDDEN + h0 + hh) * SEQ + sIn + ss) = o2;
}

// bqk[h] = sum_d bq[d] * Wk[h][d]
__global__ __launch_bounds__(64) void k_gemv_bqk(const float* __restrict__ Wk,
                                                 const float* __restrict__ bq,
                                                 float* __restrict__ bqk) {
  const int h = blockIdx.x, l = threadIdx.x;
  float s = 0.0f;
#pragma unroll
  for (int d = l; d < HIDDEN; d += 64) s += bq[d] * Wk[(long)h * HIDDEN + d];
#pragma unroll
  for (int o = 32; o > 0; o >>= 1) s += __shfl_xor(s, o);
  if (l == 0) bqk[h] = s;
}

// ---------------------------------------------------------------------------
// C[M,N] = (A[M,K].B[N,K]^T)*scale + bias[col]      (MODE 0)
//        = exp((A.B^T)*scale + maskbias[z][col])    (MODE 1, bf16 out + rowsums)
// 128x128 tile, BK=32, 4 waves, 16x16x32 MFMA, global_load_lds w16.
// K-loop: 2-barrier counted-vmcnt pipeline — raw s_barrier, prefetch issued
// between barriers, s_waitcnt vmcnt(4) keeps next tile's loads in flight
// across the barrier (no vmcnt(0) drain in steady state).
// bf16 outputs bounce through LDS for clean coalesced 16B-lane stores.
template <typename OUT, int MODE>
__global__ __launch_bounds__(256) void k_gemm_bt(
    const bf16* __restrict__ A, const bf16* __restrict__ B, OUT* __restrict__ C,
    const float* __restrict__ bias, const float* __restrict__ mask,
    float* __restrict__ rspart, int N, int K, float scale,
    int nx, int ny, int rowfast, long strA, long strB, long strC) {
  const int id = xcd_swz();
  int col, row, z;
  if (rowfast) {
    row = id % ny; col = (id / ny) % nx; z = id / (ny * nx);
  } else {
    col = id % nx; row = (id / nx) % ny; z = id / (nx * ny);
  }

  __shared__ bf16 smem[16384];  // [0,8K): A dbuf, [8K,16K): B dbuf; epilogue: C tile

  const int tid = threadIdx.x;
  const int lane = tid & 63, wave = tid >> 6;
  const int wr = wave >> 1, wc = wave & 1;
  const int lr = lane & 15, lk = (lane >> 4) * 8, lg = (lane >> 4) * 4;

  const bf16* At = A + (long)z * strA + (long)row * 128 * K;
  const bf16* Bt = B + (long)z * strB + (long)col * 128 * K;

#define STAGE_TILE(buf, k0)                                                   \
  {                                                                           \
    bf16* dA = smem + (buf) * 4096;                                           \
    bf16* dB = smem + 8192 + (buf) * 4096;                                    \
    _Pragma("unroll") for (int h = 0; h < 2; ++h) {                           \
      const int cch = tid + h * 256;                                          \
      const int rr = cch >> 2, cc = (cch & 3) * 8;                            \
      GLOAD16(At + (long)rr * K + (k0) + cc, (char*)dA + cch * 16);           \
      GLOAD16(Bt + (long)rr * K + (k0) + cc, (char*)dB + cch * 16);           \
    }                                                                         \
  }

  STAGE_TILE(0, 0);

  f32x4 acc[4][4] = {};
  const int nt = K / 32;
  int cur = 0;
#pragma unroll 1
  for (int t = 0; t < nt; ++t) {
    FENCE;
    __builtin_amdgcn_s_barrier();  // B0: all reads of buf cur^1 (tile t-1) done
    FENCE;
    if (t + 1 < nt) {
      STAGE_TILE(cur ^ 1, (t + 1) * 32);
      asm volatile("s_waitcnt vmcnt(4)" ::: "memory");  // tile t landed; t+1 in flight
    } else {
      asm volatile("s_waitcnt vmcnt(0)" ::: "memory");
    }
    __builtin_amdgcn_s_barrier();  // B1: tile t resident for every thread
    FENCE;
    const bf16* rA = smem + cur * 4096;
    const bf16* rB = smem + 8192 + cur * 4096;
    bf16x8 af[4], bfr[4];
#pragma unroll
    for (int m = 0; m < 4; ++m)
      af[m] = *reinterpret_cast<const bf16x8*>(&rA[(wr * 64 + m * 16 + lr) * 32 + lk]);
#pragma unroll
    for (int n = 0; n < 4; ++n)
      bfr[n] = *reinterpret_cast<const bf16x8*>(&rB[(wc * 64 + n * 16 + lr) * 32 + lk]);
    __builtin_amdgcn_s_setprio(1);
#pragma unroll
    for (int m = 0; m < 4; ++m)
#pragma unroll
      for (int n = 0; n < 4; ++n)
        acc[m][n] = __builtin_amdgcn_mfma_f32_16x16x32_bf16(af[m], bfr[n], acc[m][n], 0, 0, 0);
    __builtin_amdgcn_s_setprio(0);
    cur ^= 1;
  }
#undef STAGE_TILE

  if constexpr (__is_same(OUT, float)) {
    float* Cb = (float*)C + (long)z * strC;
#pragma unroll
    for (int m = 0; m < 4; ++m)
#pragma unroll
      for (int n = 0; n < 4; ++n) {
        const int gc = col * 128 + wc * 64 + n * 16 + lr;
        const float bv = bias ? bias[gc] : 0.0f;
#pragma unroll
        for (int j = 0; j < 4; ++j) {
          const int gr = row * 128 + wr * 64 + m * 16 + lg + j;
          Cb[(long)gr * N + gc] = acc[m][n][j] * scale + bv;
        }
      }
  } else {
    FENCE;
    __builtin_amdgcn_s_barrier();  // staging LDS now reused as C tile
    FENCE;
    float rsv[4][4];
    if constexpr (MODE == 1) {
#pragma unroll
      for (int m = 0; m < 4; ++m)
#pragma unroll
        for (int j = 0; j < 4; ++j) rsv[m][j] = 0.0f;
    }
#pragma unroll
    for (int m = 0; m < 4; ++m)
#pragma unroll
      for (int n = 0; n < 4; ++n) {
        const int gc = col * 128 + wc * 64 + n * 16 + lr;
        float bv = 0.0f, mbv = 0.0f;
        if constexpr (MODE == 0) bv = bias ? bias[gc] : 0.0f;
        if constexpr (MODE == 1) mbv = (1.0f - mask[(long)z * SEQ + gc]) * -10000.0f;
#pragma unroll
        for (int j = 0; j < 4; ++j) {
          float v = acc[m][n][j] * scale;
          if constexpr (MODE == 1) {
            v = expf(v + mbv);
            rsv[m][j] += v;
          } else {
            v += bv;
          }
          smem[(wr * 64 + m * 16 + lg + j) * 128 + wc * 64 + n * 16 + lr] = (bf16)v;
        }
      }
    if constexpr (MODE == 1) {
      // per-row partial sums over this wave's 64 cols -> unique slot (no atomics)
#pragma unroll
      for (int m = 0; m < 4; ++m)
#pragma unroll
        for (int j = 0; j < 4; ++j) {
          float v = rsv[m][j];
          v += __shfl_xor(v, 1); v += __shfl_xor(v, 2);
          v += __shfl_xor(v, 4); v += __shfl_xor(v, 8);
          if ((lane & 15) == 0) {
            const int gr = row * 128 + wr * 64 + m * 16 + lg + j;
            rspart[((long)z * NQ + gr) * 128 + col * 2 + wc] = v;
          }
        }
    }
    __syncthreads();
    OUT* Cb = C + (long)z * strC;
    const long rb = (long)row * 128, cb = (long)col * 128;
#pragma unroll
    for (int i = 0; i < 8; ++i) {
      const int ch = tid + i * 256;     // 2048 chunks of 16B
      const int rr = ch >> 4;
      const int ce = (ch & 15) * 8;
      *reinterpret_cast<bf16x8*>(&Cb[(rb + rr) * N + cb + ce]) =
          *reinterpret_cast<const bf16x8*>(smem + ch * 8);
    }
  }
}

// rowsum[row] = sum of 128 partial slots (deterministic reduce)
__global__ __launch_bounds__(256) void k_rowsum(const float* __restrict__ rp,
                                                float* __restrict__ rs) {
  const int t = threadIdx.x;
  const int row = blockIdx.x * 8 + (t >> 5);
  const int s = t & 31;
  const float* base = rp + (long)row * 128;
  float v = base[s] + base[s + 32] + base[s + 64] + base[s + 96];
  v += __shfl_xor(v, 1); v += __shfl_xor(v, 2); v += __shfl_xor(v, 4);
  v += __shfl_xor(v, 8); v += __shfl_xor(v, 16);
  if (s == 0) rs[row] = v;
}

// ---------------------------------------------------------------------------
// PHS split-K partial GEMM: Cpart[kc][b,q,:] = P[b, q-tile, kc-chunk] . hsT^T
// Same 2-barrier counted-vmcnt loop + LDS-bounced bf16 writes.
#define PHS_KC (SEQ / PHS_KS)
__global__ __launch_bounds__(256) void k_gemm_phs(const bf16* __restrict__ P,
                                                  const bf16* __restrict__ HT,
                                                  bf16* __restrict__ Cp) {
  const int id = xcd_swz();
  const int col = id % 6;
  int r = id / 6;
  const int row = r % 8;
  r /= 8;
  const int b = r % 4;
  const int kc = r / 4;

  __shared__ bf16 smem[16384];

  const int tid = threadIdx.x;
  const int lane = tid & 63, wave = tid >> 6;
  const int wr = wave >> 1, wc = wave & 1;
  const int lr = lane & 15, lk = (lane >> 4) * 8, lg = (lane >> 4) * 4;

  const bf16* At = P + (long)b * NQ * SEQ + (long)row * 128 * SEQ + (long)kc * PHS_KC;
  const bf16* Bt = HT + (long)b * HIDDEN * SEQ + (long)col * 128 * SEQ + (long)kc * PHS_KC;

#define STAGE_PHS(buf, k0)                                                    \
  {                                                                           \
    bf16* dA = smem + (buf) * 4096;                                           \
    bf16* dB = smem + 8192 + (buf) * 4096;                                    \
    _Pragma("unroll") for (int h = 0; h < 2; ++h) {                           \
      const int cch = tid + h * 256;                                          \
      const int rr = cch >> 2, cc = (cch & 3) * 8;                            \
      GLOAD16(At + (long)rr * SEQ + (k0) + cc, (char*)dA + cch * 16);         \
      GLOAD16(Bt + (long)rr * SEQ + (k0) + cc, (char*)dB + cch * 16);         \
    }                                                                         \
  }

  STAGE_PHS(0, 0);

  f32x4 acc[4][4] = {};
  const int nt = PHS_KC / 32;
  int cur = 0;
#pragma unroll 1
  for (int t = 0; t < nt; ++t) {
    FENCE;
    __builtin_amdgcn_s_barrier();
    FENCE;
    if (t + 1 < nt) {
      STAGE_PHS(cur ^ 1, (t + 1) * 32);
      asm volatile("s_waitcnt vmcnt(4)" ::: "memory");
    } else {
      asm volatile("s_waitcnt vmcnt(0)" ::: "memory");
    }
    __builtin_amdgcn_s_barrier();
    FENCE;
    const bf16* rA = smem + cur * 4096;
    const bf16* rB = smem + 8192 + cur * 4096;
    bf16x8 af[4], bfr[4];
#pragma unroll
    for (int m = 0; m < 4; ++m)
      af[m] = *reinterpret_cast<const bf16x8*>(&rA[(wr * 64 + m * 16 + lr) * 32 + lk]);
#pragma unroll
    for (int n = 0; n < 4; ++n)
      bfr[n] = *reinterpret_cast<const bf16x8*>(&rB[(wc * 64 + n * 16 + lr) * 32 + lk]);
    __builtin_amdgcn_s_setprio(1);
#pragma unroll
    for (int m = 0; m < 4; ++m)
#pragma unroll
      for (int n = 0; n < 4; ++n)
        acc[m][n] = __builtin_amdgcn_mfma_f32_16x16x32_bf16(af[m], bfr[n], acc[m][n], 0, 0, 0);
    __builtin_amdgcn_s_setprio(0);
    cur ^= 1;
  }
#undef STAGE_PHS

  FENCE;
  __builtin_amdgcn_s_barrier();
  FENCE;
#pragma unroll
  for (int m = 0; m < 4; ++m)
#pragma unroll
    for (int n = 0; n < 4; ++n)
#pragma unroll
      for (int j = 0; j < 4; ++j)
        smem[(wr * 64 + m * 16 + lg + j) * 128 + wc * 64 + n * 16 + lr] =
            (bf16)acc[m][n][j];
  __syncthreads();
  bf16* Co = Cp + ((long)kc * BATCH + b) * NQ * HIDDEN;
  const long rb = (long)row * 128, cb = (long)col * 128;
#pragma unroll
  for (int i = 0; i < 8; ++i) {
    const int ch = tid + i * 256;
    const int rr = ch >> 4;
    const int ce = (ch & 15) * 8;
    *reinterpret_cast<bf16x8*>(&Co[(rb + rr) * HIDDEN + cb + ce]) =
        *reinterpret_cast<const bf16x8*>(smem + ch * 8);
  }
}

// ctx1 = (sum of 8 bf16 partials) / rowsum[row]   (fp32 accumulate, bf16 out)
__global__ __launch_bounds__(256) void k_reduce8(const bf16* __restrict__ p,
                                                 const float* __restrict__ rs,
                                                 bf16* __restrict__ out, int n8) {
  const long NB = (long)BATCH * NQ * HIDDEN;
  const int stride = gridDim.x * blockDim.x;
  for (int i = blockIdx.x * blockDim.x + threadIdx.x; i < n8; i += stride) {
    float acc[8] = {};
#pragma unroll
    for (int k = 0; k < PHS_KS; ++k) {
      bf16x8 v = reinterpret_cast<const bf16x8*>(p + k * NB)[i];
#pragma unroll
      for (int j = 0; j < 8; ++j) acc[j] += (float)v[j];
    }
    const float inv = 1.0f / rs[i / 96];  // 96 vec8-chunks per 768-col row
    bf16x8 o;
#pragma unroll
    for (int j = 0; j < 8; ++j) o[j] = (bf16)(acc[j] * inv);
    reinterpret_cast<bf16x8*>(out)[i] = o;
  }
}

// ---------------------------------------------------------------------------
extern "C" void kernel_launch(void* const* d_in, const int* in_sizes, int n_in,
                              void* d_out, int out_size, void* d_ws, size_t ws_size,
                              hipStream_t stream) {
  const float* hs = (const float*)d_in[0];    // [B,S,H]
  const float* qu = (const float*)d_in[1];    // [B,Q,H]
  const float* mask = (const float*)d_in[2];  // [B,S]
  const float* Wq = (const float*)d_in[3];
  const float* bq = (const float*)d_in[4];
  const float* Wk = (const float*)d_in[5];
  const float* Wv = (const float*)d_in[7];
  const float* bv = (const float*)d_in[8];
  float* out = (float*)d_out;  // [B,Q,H] fp32
  // bk (d_in[6]) adds a softmax-row-constant -> cancels exactly.

  const size_t HS_N = (size_t)BATCH * SEQ * HIDDEN;
  const size_t QU_N = (size_t)BATCH * NQ * HIDDEN;
  const size_t W_N = (size_t)HIDDEN * HIDDEN;
  const size_t P_N = (size_t)BATCH * NQ * SEQ;

  char* ws = (char*)d_ws;
  size_t off = 0;
  auto alloc = [&](size_t bytes) {
    char* p = ws + off;
    off += (bytes + 255) & ~(size_t)255;
    return p;
  };

  // regionA: hsb (live through scores) / PHS partials (after) — exact overlap
  char* regionA = alloc(HS_N * 2);
  bf16* hsb = (bf16*)regionA;
  bf16* Ppart = (bf16*)regionA;         // PHS_KS * QU_N bf16 = HS_N*2 bytes
  bf16* hsT = (bf16*)alloc(HS_N * 2);   // [B][H][S]
  bf16* Pr = (bf16*)alloc(P_N * 2);     // unnormalized probs exp(s+mb)
  bf16* qub = (bf16*)alloc(QU_N * 2);
  bf16* tmpb = (bf16*)alloc(QU_N * 2);  // folded query: qu.(Wq.Wk^T) + bq.Wk^T
  bf16* ctx1 = (bf16*)alloc(QU_N * 2);  // (P.hs)/rowsum
  bf16* Wkb = (bf16*)alloc(W_N * 2);
  bf16* Wqb = (bf16*)alloc(W_N * 2);
  bf16* WvT = (bf16*)alloc(W_N * 2);
  bf16* Mt = (bf16*)alloc(W_N * 2);     // Wk.Wq^T
  float* bqk = (float*)alloc(HIDDEN * 4);
  float* rspart = (float*)alloc((size_t)BATCH * NQ * 128 * 4);  // 2 MB
  float* rowsum = (float*)alloc((size_t)BATCH * NQ * 4);

  // 1) converts + fused hs prep
  k_cvt<<<dim3(1024), dim3(256), 0, stream>>>(qu, qub, (int)(QU_N / 4));
  k_cvt<<<dim3(576), dim3(256), 0, stream>>>(Wk, Wkb, (int)(W_N / 4));
  k_cvt<<<dim3(576), dim3(256), 0, stream>>>(Wq, Wqb, (int)(W_N / 4));
  k_transpose_w<<<dim3(24, 24), dim3(256), 0, stream>>>(Wv, WvT, HIDDEN, HIDDEN);
  k_cvt_hs_dual<<<dim3(12, 1024), dim3(256), 0, stream>>>(hs, hsb, hsT);
  k_gemv_bqk<<<dim3(768), dim3(64), 0, stream>>>(Wk, bq, bqk);

  // 2) Mt = Wk.Wq^T  [768x768]
  k_gemm_bt<bf16, 0><<<dim3(36), dim3(256), 0, stream>>>(
      Wkb, Wqb, Mt, nullptr, nullptr, nullptr, HIDDEN, HIDDEN, 1.0f, 6, 6, 0, 0, 0, 0);

  // 3) folded query: tmp = qub.Mt^T + bqk  [4096x768]
  k_gemm_bt<bf16, 0><<<dim3(192), dim3(256), 0, stream>>>(
      qub, Mt, tmpb, bqk, nullptr, nullptr, HIDDEN, HIDDEN, 1.0f, 6, 32, 0, 0, 0, 0);

  // 4) scores: Pr = exp(tmp.hsb^T/sqrt(H) + maskbias), rowsum partials
  const float qkscale = 1.0f / sqrtf((float)HIDDEN);
  k_gemm_bt<bf16, 1><<<dim3(2048), dim3(256), 0, stream>>>(
      tmpb, hsb, Pr, nullptr, mask, rspart, SEQ, HIDDEN, qkscale, 64, 8, 1,
      (long)NQ * HIDDEN, (long)SEQ * HIDDEN, (long)NQ * SEQ);
  k_rowsum<<<dim3(BATCH * NQ / 8), dim3(256), 0, stream>>>(rspart, rowsum);

  // 5) PHS partials: Ppart[kc] = P[:, kc-chunk] . hsT^T  (overwrites dead hsb)
  k_gemm_phs<<<dim3(6 * 8 * 4 * PHS_KS), dim3(256), 0, stream>>>(Pr, hsT, Ppart);

  // 6) ctx1 = (sum partials) / rowsum
  k_reduce8<<<dim3(1536), dim3(256), 0, stream>>>(Ppart, rowsum, ctx1, (int)(QU_N / 8));

  // 7) V-fold: out = ctx1.Wv + bv  (sum_j p = 1 makes +bv exact)
  k_gemm_bt<float, 0><<<dim3(192), dim3(256), 0, stream>>>(
      ctx1, WvT, out, bv, nullptr, nullptr, HIDDEN, HIDDEN, 1.0f, 6, 32, 0, 0, 0, 0);
}